// Round 2
// baseline (22562.085 us; speedup 1.0000x reference)
//
#include <hip/hip_runtime.h>

// Fast-mode NLM, PATCH=5 (o=2), DIST=6 -> 169 shifts, h=0.05.
// w = exp(-16*boxsum) = exp2(NEGC*boxsum), NEGC = -16*log2(e).
//
// Round-2 design:
//  * tile 64x96 per block, thread = 4 cols x 6 rows (16x16 block)
//  * LDS stride 84 dwords (mod-4 aligned) -> all reads are aligned ds_read_b128
//  * dx-paired shifts (dx, dx+1) share u-reads and one 3xfloat4 s-read
//  * window misalignment handled by compile-time M = (dx+2)&3 selection
//  * ALL register arrays replaced by named vars / literal-token macros (rule #20)

#define HH 768
#define WW 768
#define TW 64
#define TH 96
#define LR 112            // TH + 16
#define LSF 84            // LDS row stride in dwords (multiple of 4!)
#define LS4 21            // row stride in float4
#define NEGC (-23.083120654223414f)   // -16 * log2(e)

__device__ __forceinline__ float sqf(float t){ return t*t; }

template<int I>
__device__ __forceinline__ float g3(const float4& a, const float4& b, const float4& c){
  if constexpr (I==0) return a.x; else if constexpr (I==1) return a.y;
  else if constexpr (I==2) return a.z; else if constexpr (I==3) return a.w;
  else if constexpr (I==4) return b.x; else if constexpr (I==5) return b.y;
  else if constexpr (I==6) return b.z; else if constexpr (I==7) return b.w;
  else if constexpr (I==8) return c.x; else if constexpr (I==9) return c.y;
  else if constexpr (I==10) return c.z; else return c.w;
}

struct Acc {
  float4 n0,n1,n2,n3,n4,n5;
  float4 d0,d1,d2,d3,d4,d5;
};

// squared diff: u-window position UI (2..9), s-window position SI (M..M+8)
#define SQA(UI,SI) sqf(g3<(UI)>(u0,u1,u2) - g3<(SI)>(s0,s1,s2))

// horizontal 5-window sliding row sums for 4 output cols; O=0 (shift a) / 1 (shift b)
#define QROW(RN, O) \
  { float q0=SQA(2,M+0+O), q1=SQA(3,M+1+O), q2=SQA(4,M+2+O), q3=SQA(5,M+3+O), \
          q4=SQA(6,M+4+O), q5=SQA(7,M+5+O), q6=SQA(8,M+6+O), q7=SQA(9,M+7+O); \
    RN.x = ((q0+q1)+(q2+q3))+q4; \
    RN.y = RN.x - q0 + q5; \
    RN.z = RN.y - q1 + q6; \
    RN.w = RN.z - q2 + q7; }

// capture shifted center values s[M+2..M+6] into value-ring slot T (5 floats)
#define DOCAP(T) \
  c##T##0 = g3<M+2>(s0,s1,s2); c##T##1 = g3<M+3>(s0,s1,s2); \
  c##T##2 = g3<M+4>(s0,s1,s2); c##T##3 = g3<M+5>(s0,s1,s2); \
  c##T##4 = g3<M+6>(s0,s1,s2);
#define NOCAP

// one row event for a dx-pair: 6 aligned b128 reads, two row-sums, ring update R
#define EVP(E, R, CAP) { \
  const float4 u0 = Lv[ub + (E)*LS4    ]; \
  const float4 u1 = Lv[ub + (E)*LS4 + 1]; \
  const float4 u2 = Lv[ub + (E)*LS4 + 2]; \
  const float4 s0 = Lv[sb + (E)*LS4    ]; \
  const float4 s1 = Lv[sb + (E)*LS4 + 1]; \
  const float4 s2 = Lv[sb + (E)*LS4 + 2]; \
  float4 ran, rbn; \
  QROW(ran, 0) \
  QROW(rbn, 1) \
  dsa.x += ran.x - ra##R.x; dsa.y += ran.y - ra##R.y; \
  dsa.z += ran.z - ra##R.z; dsa.w += ran.w - ra##R.w; \
  ra##R = ran; \
  dsb.x += rbn.x - rb##R.x; dsb.y += rbn.y - rb##R.y; \
  dsb.z += rbn.z - rb##R.z; dsb.w += rbn.w - rb##R.w; \
  rb##R = rbn; \
  CAP }

// emit output row K for the pair using value-ring slot T
#define STEPP(K, T) { \
  float4 wa, wb; \
  wa.x = exp2f(dsa.x*NEGC); wa.y = exp2f(dsa.y*NEGC); \
  wa.z = exp2f(dsa.z*NEGC); wa.w = exp2f(dsa.w*NEGC); \
  wb.x = exp2f(dsb.x*NEGC); wb.y = exp2f(dsb.y*NEGC); \
  wb.z = exp2f(dsb.z*NEGC); wb.w = exp2f(dsb.w*NEGC); \
  acc.n##K.x += wa.x*c##T##0 + wb.x*c##T##1; \
  acc.n##K.y += wa.y*c##T##1 + wb.y*c##T##2; \
  acc.n##K.z += wa.z*c##T##2 + wb.z*c##T##3; \
  acc.n##K.w += wa.w*c##T##3 + wb.w*c##T##4; \
  acc.d##K.x += wa.x + wb.x; acc.d##K.y += wa.y + wb.y; \
  acc.d##K.z += wa.z + wb.z; acc.d##K.w += wa.w + wb.w; }

template<int M>
__device__ __forceinline__ void do_pair(const float4* __restrict__ Lv, int ub, int sb, Acc& acc)
{
  float4 ra0{},ra1{},ra2{},ra3{},ra4{};
  float4 rb0{},rb1{},rb2{},rb3{},rb4{};
  float4 dsa{}, dsb{};
  float cP0,cP1,cP2,cP3,cP4;
  float cQ0,cQ1,cQ2,cQ3,cQ4;
  float cR0,cR1,cR2,cR3,cR4;
  EVP(0,0,NOCAP)
  EVP(1,1,NOCAP)
  EVP(2,2,DOCAP(P))
  EVP(3,3,DOCAP(Q))
  EVP(4,4,DOCAP(R))
  STEPP(0,P)
  EVP(5,0,DOCAP(P))
  STEPP(1,Q)
  EVP(6,1,DOCAP(Q))
  STEPP(2,R)
  EVP(7,2,DOCAP(R))
  STEPP(3,P)
  EVP(8,3,NOCAP)
  STEPP(4,Q)
  EVP(9,4,NOCAP)
  STEPP(5,R)
}

// ---- single-shift variant (dx = +6, M = 0): only the a-channel ----
#define EVS(E, R, CAP) { \
  const float4 u0 = Lv[ub + (E)*LS4    ]; \
  const float4 u1 = Lv[ub + (E)*LS4 + 1]; \
  const float4 u2 = Lv[ub + (E)*LS4 + 2]; \
  const float4 s0 = Lv[sb + (E)*LS4    ]; \
  const float4 s1 = Lv[sb + (E)*LS4 + 1]; \
  const float4 s2 = s1; /* never referenced for M=0 */ \
  float4 ran; \
  QROW(ran, 0) \
  dsa.x += ran.x - ra##R.x; dsa.y += ran.y - ra##R.y; \
  dsa.z += ran.z - ra##R.z; dsa.w += ran.w - ra##R.w; \
  ra##R = ran; \
  CAP }

#define STEPS(K, T) { \
  float4 wa; \
  wa.x = exp2f(dsa.x*NEGC); wa.y = exp2f(dsa.y*NEGC); \
  wa.z = exp2f(dsa.z*NEGC); wa.w = exp2f(dsa.w*NEGC); \
  acc.n##K.x += wa.x*c##T##0; \
  acc.n##K.y += wa.y*c##T##1; \
  acc.n##K.z += wa.z*c##T##2; \
  acc.n##K.w += wa.w*c##T##3; \
  acc.d##K.x += wa.x; acc.d##K.y += wa.y; \
  acc.d##K.z += wa.z; acc.d##K.w += wa.w; }

__device__ __forceinline__ void do_single(const float4* __restrict__ Lv, int ub, int sb, Acc& acc)
{
  constexpr int M = 0;
  float4 ra0{},ra1{},ra2{},ra3{},ra4{};
  float4 dsa{};
  float cP0,cP1,cP2,cP3,cP4;
  float cQ0,cQ1,cQ2,cQ3,cQ4;
  float cR0,cR1,cR2,cR3,cR4;
  EVS(0,0,NOCAP)
  EVS(1,1,NOCAP)
  EVS(2,2,DOCAP(P))
  EVS(3,3,DOCAP(Q))
  EVS(4,4,DOCAP(R))
  STEPS(0,P)
  EVS(5,0,DOCAP(P))
  STEPS(1,Q)
  EVS(6,1,DOCAP(Q))
  STEPS(2,R)
  EVS(7,2,DOCAP(R))
  STEPS(3,P)
  EVS(8,3,NOCAP)
  STEPS(4,Q)
  EVS(9,4,NOCAP)
  STEPS(5,R)
}

__global__ __launch_bounds__(256, 3)
void nlm_kernel(const float* __restrict__ in, float* __restrict__ out)
{
  __shared__ float4 Lv[LR * LS4];
  float* Lf = (float*)Lv;

  const int plane = blockIdx.z;
  const int ty0 = blockIdx.y * TH;
  const int tx0 = blockIdx.x * TW;
  const float* __restrict__ src = in + (size_t)plane * (HH * WW);

  // stage 112x80 reflect-padded, clipped tile (cols 80..83 of each row unused)
  const int tid = threadIdx.y * 16 + threadIdx.x;
  for (int idx = tid; idx < LR * 80; idx += 256) {
    int r = idx / 80;
    int c = idx - r * 80;
    int gy = ty0 - 8 + r;
    int gx = tx0 - 8 + c;
    gy = (gy < 0) ? -gy : ((gy >= HH) ? 2 * HH - 2 - gy : gy);
    gx = (gx < 0) ? -gx : ((gx >= WW) ? 2 * WW - 2 - gx : gx);
    float v = src[gy * WW + gx];
    Lf[r * LSF + c] = fminf(fmaxf(v, 0.0f), 1.0f);
  }
  __syncthreads();

  const int tx = threadIdx.x;          // 4 output cols: LDS dwords 4tx+8..4tx+11
  const int ty = threadIdx.y;          // 6 output rows starting at 6*ty
  const int ub = (6 * ty + 6) * LS4 + tx + 1;   // f4 idx of u-read row base

  Acc acc{};

#pragma unroll 1
  for (int dy = -6; dy <= 6; ++dy) {
    const int sb0 = ub - 1 + dy * LS4;
#pragma unroll 1
    for (int c3 = 0; c3 < 3; ++c3) {
      // dx = -6+4*c3 (windows M=0,1) and dx = -4+4*c3 (windows M=2,3)
      do_pair<0>(Lv, ub, sb0 + c3, acc);
      do_pair<2>(Lv, ub, sb0 + c3, acc);
    }
    do_single(Lv, ub, sb0 + 3, acc);   // dx = +6
  }

  float* dst = out + (size_t)plane * (HH * WW)
             + (size_t)(ty0 + 6 * ty) * WW + (tx0 + 4 * tx);
#define OUTK(K) { float4 o; \
  o.x = acc.n##K.x / acc.d##K.x; o.y = acc.n##K.y / acc.d##K.y; \
  o.z = acc.n##K.z / acc.d##K.z; o.w = acc.n##K.w / acc.d##K.w; \
  *reinterpret_cast<float4*>(dst + (K) * WW) = o; }
  OUTK(0) OUTK(1) OUTK(2) OUTK(3) OUTK(4) OUTK(5)
#undef OUTK
}

extern "C" void kernel_launch(void* const* d_in, const int* in_sizes, int n_in,
                              void* d_out, int out_size, void* d_ws, size_t ws_size,
                              hipStream_t stream) {
  const float* x = (const float*)d_in[0];
  float* out = (float*)d_out;
  dim3 grid(WW / TW, HH / TH, 32);   // 12 x 8 x 32 = 3072 blocks
  dim3 block(16, 16);
  nlm_kernel<<<grid, block, 0, stream>>>(x, out);
}

// Round 3
// 12237.055 us; speedup vs baseline: 1.8438x; 1.8438x over previous
//
#include <hip/hip_runtime.h>

// Fast-mode NLM, PATCH=5 (o=2), DIST=6 -> 169 shifts, h=0.05.
// w = exp(-16*boxsum) = exp2(NEGC*boxsum), NEGC = -16*log2(e).
//
// Round-3 change (single variable): __launch_bounds__(256, 3) -> (256, 2).
// R2's counters showed a scratch spill round-trip (FETCH 36.9 GB ~= WRITE
// 40.9 GB, VGPR_Count stuck at 84): peak live ~161 VGPRs vs the 168 cap
// implied by min-3-waves/EU, so the allocator demoted the Acc struct and
// the sliding-window rings to scratch. Cap 256 gives it headroom; occupancy
// is LDS-limited (37.9 KB -> 3 blocks/CU) regardless.

#define HH 768
#define WW 768
#define TW 64
#define TH 96
#define LR 112            // TH + 16
#define LSF 84            // LDS row stride in dwords (multiple of 4!)
#define LS4 21            // row stride in float4
#define NEGC (-23.083120654223414f)   // -16 * log2(e)

__device__ __forceinline__ float sqf(float t){ return t*t; }

template<int I>
__device__ __forceinline__ float g3(const float4& a, const float4& b, const float4& c){
  if constexpr (I==0) return a.x; else if constexpr (I==1) return a.y;
  else if constexpr (I==2) return a.z; else if constexpr (I==3) return a.w;
  else if constexpr (I==4) return b.x; else if constexpr (I==5) return b.y;
  else if constexpr (I==6) return b.z; else if constexpr (I==7) return b.w;
  else if constexpr (I==8) return c.x; else if constexpr (I==9) return c.y;
  else if constexpr (I==10) return c.z; else return c.w;
}

struct Acc {
  float4 n0,n1,n2,n3,n4,n5;
  float4 d0,d1,d2,d3,d4,d5;
};

// squared diff: u-window position UI (2..9), s-window position SI (M..M+8)
#define SQA(UI,SI) sqf(g3<(UI)>(u0,u1,u2) - g3<(SI)>(s0,s1,s2))

// horizontal 5-window sliding row sums for 4 output cols; O=0 (shift a) / 1 (shift b)
#define QROW(RN, O) \
  { float q0=SQA(2,M+0+O), q1=SQA(3,M+1+O), q2=SQA(4,M+2+O), q3=SQA(5,M+3+O), \
          q4=SQA(6,M+4+O), q5=SQA(7,M+5+O), q6=SQA(8,M+6+O), q7=SQA(9,M+7+O); \
    RN.x = ((q0+q1)+(q2+q3))+q4; \
    RN.y = RN.x - q0 + q5; \
    RN.z = RN.y - q1 + q6; \
    RN.w = RN.z - q2 + q7; }

// capture shifted center values s[M+2..M+6] into value-ring slot T (5 floats)
#define DOCAP(T) \
  c##T##0 = g3<M+2>(s0,s1,s2); c##T##1 = g3<M+3>(s0,s1,s2); \
  c##T##2 = g3<M+4>(s0,s1,s2); c##T##3 = g3<M+5>(s0,s1,s2); \
  c##T##4 = g3<M+6>(s0,s1,s2);
#define NOCAP

// one row event for a dx-pair: 6 aligned b128 reads, two row-sums, ring update R
#define EVP(E, R, CAP) { \
  const float4 u0 = Lv[ub + (E)*LS4    ]; \
  const float4 u1 = Lv[ub + (E)*LS4 + 1]; \
  const float4 u2 = Lv[ub + (E)*LS4 + 2]; \
  const float4 s0 = Lv[sb + (E)*LS4    ]; \
  const float4 s1 = Lv[sb + (E)*LS4 + 1]; \
  const float4 s2 = Lv[sb + (E)*LS4 + 2]; \
  float4 ran, rbn; \
  QROW(ran, 0) \
  QROW(rbn, 1) \
  dsa.x += ran.x - ra##R.x; dsa.y += ran.y - ra##R.y; \
  dsa.z += ran.z - ra##R.z; dsa.w += ran.w - ra##R.w; \
  ra##R = ran; \
  dsb.x += rbn.x - rb##R.x; dsb.y += rbn.y - rb##R.y; \
  dsb.z += rbn.z - rb##R.z; dsb.w += rbn.w - rb##R.w; \
  rb##R = rbn; \
  CAP }

// emit output row K for the pair using value-ring slot T
#define STEPP(K, T) { \
  float4 wa, wb; \
  wa.x = exp2f(dsa.x*NEGC); wa.y = exp2f(dsa.y*NEGC); \
  wa.z = exp2f(dsa.z*NEGC); wa.w = exp2f(dsa.w*NEGC); \
  wb.x = exp2f(dsb.x*NEGC); wb.y = exp2f(dsb.y*NEGC); \
  wb.z = exp2f(dsb.z*NEGC); wb.w = exp2f(dsb.w*NEGC); \
  acc.n##K.x += wa.x*c##T##0 + wb.x*c##T##1; \
  acc.n##K.y += wa.y*c##T##1 + wb.y*c##T##2; \
  acc.n##K.z += wa.z*c##T##2 + wb.z*c##T##3; \
  acc.n##K.w += wa.w*c##T##3 + wb.w*c##T##4; \
  acc.d##K.x += wa.x + wb.x; acc.d##K.y += wa.y + wb.y; \
  acc.d##K.z += wa.z + wb.z; acc.d##K.w += wa.w + wb.w; }

template<int M>
__device__ __forceinline__ void do_pair(const float4* __restrict__ Lv, int ub, int sb, Acc& acc)
{
  float4 ra0{},ra1{},ra2{},ra3{},ra4{};
  float4 rb0{},rb1{},rb2{},rb3{},rb4{};
  float4 dsa{}, dsb{};
  float cP0,cP1,cP2,cP3,cP4;
  float cQ0,cQ1,cQ2,cQ3,cQ4;
  float cR0,cR1,cR2,cR3,cR4;
  EVP(0,0,NOCAP)
  EVP(1,1,NOCAP)
  EVP(2,2,DOCAP(P))
  EVP(3,3,DOCAP(Q))
  EVP(4,4,DOCAP(R))
  STEPP(0,P)
  EVP(5,0,DOCAP(P))
  STEPP(1,Q)
  EVP(6,1,DOCAP(Q))
  STEPP(2,R)
  EVP(7,2,DOCAP(R))
  STEPP(3,P)
  EVP(8,3,NOCAP)
  STEPP(4,Q)
  EVP(9,4,NOCAP)
  STEPP(5,R)
}

// ---- single-shift variant (dx = +6, M = 0): only the a-channel ----
#define EVS(E, R, CAP) { \
  const float4 u0 = Lv[ub + (E)*LS4    ]; \
  const float4 u1 = Lv[ub + (E)*LS4 + 1]; \
  const float4 u2 = Lv[ub + (E)*LS4 + 2]; \
  const float4 s0 = Lv[sb + (E)*LS4    ]; \
  const float4 s1 = Lv[sb + (E)*LS4 + 1]; \
  const float4 s2 = s1; /* never referenced for M=0 */ \
  float4 ran; \
  QROW(ran, 0) \
  dsa.x += ran.x - ra##R.x; dsa.y += ran.y - ra##R.y; \
  dsa.z += ran.z - ra##R.z; dsa.w += ran.w - ra##R.w; \
  ra##R = ran; \
  CAP }

#define STEPS(K, T) { \
  float4 wa; \
  wa.x = exp2f(dsa.x*NEGC); wa.y = exp2f(dsa.y*NEGC); \
  wa.z = exp2f(dsa.z*NEGC); wa.w = exp2f(dsa.w*NEGC); \
  acc.n##K.x += wa.x*c##T##0; \
  acc.n##K.y += wa.y*c##T##1; \
  acc.n##K.z += wa.z*c##T##2; \
  acc.n##K.w += wa.w*c##T##3; \
  acc.d##K.x += wa.x; acc.d##K.y += wa.y; \
  acc.d##K.z += wa.z; acc.d##K.w += wa.w; }

__device__ __forceinline__ void do_single(const float4* __restrict__ Lv, int ub, int sb, Acc& acc)
{
  constexpr int M = 0;
  float4 ra0{},ra1{},ra2{},ra3{},ra4{};
  float4 dsa{};
  float cP0,cP1,cP2,cP3,cP4;
  float cQ0,cQ1,cQ2,cQ3,cQ4;
  float cR0,cR1,cR2,cR3,cR4;
  EVS(0,0,NOCAP)
  EVS(1,1,NOCAP)
  EVS(2,2,DOCAP(P))
  EVS(3,3,DOCAP(Q))
  EVS(4,4,DOCAP(R))
  STEPS(0,P)
  EVS(5,0,DOCAP(P))
  STEPS(1,Q)
  EVS(6,1,DOCAP(Q))
  STEPS(2,R)
  EVS(7,2,DOCAP(R))
  STEPS(3,P)
  EVS(8,3,NOCAP)
  STEPS(4,Q)
  EVS(9,4,NOCAP)
  STEPS(5,R)
}

__global__ __launch_bounds__(256, 2)
void nlm_kernel(const float* __restrict__ in, float* __restrict__ out)
{
  __shared__ float4 Lv[LR * LS4];
  float* Lf = (float*)Lv;

  const int plane = blockIdx.z;
  const int ty0 = blockIdx.y * TH;
  const int tx0 = blockIdx.x * TW;
  const float* __restrict__ src = in + (size_t)plane * (HH * WW);

  // stage 112x80 reflect-padded, clipped tile (cols 80..83 of each row unused)
  const int tid = threadIdx.y * 16 + threadIdx.x;
  for (int idx = tid; idx < LR * 80; idx += 256) {
    int r = idx / 80;
    int c = idx - r * 80;
    int gy = ty0 - 8 + r;
    int gx = tx0 - 8 + c;
    gy = (gy < 0) ? -gy : ((gy >= HH) ? 2 * HH - 2 - gy : gy);
    gx = (gx < 0) ? -gx : ((gx >= WW) ? 2 * WW - 2 - gx : gx);
    float v = src[gy * WW + gx];
    Lf[r * LSF + c] = fminf(fmaxf(v, 0.0f), 1.0f);
  }
  __syncthreads();

  const int tx = threadIdx.x;          // 4 output cols: LDS dwords 4tx+8..4tx+11
  const int ty = threadIdx.y;          // 6 output rows starting at 6*ty
  const int ub = (6 * ty + 6) * LS4 + tx + 1;   // f4 idx of u-read row base

  Acc acc{};

#pragma unroll 1
  for (int dy = -6; dy <= 6; ++dy) {
    const int sb0 = ub - 1 + dy * LS4;
#pragma unroll 1
    for (int c3 = 0; c3 < 3; ++c3) {
      // dx = -6+4*c3 (windows M=0,1) and dx = -4+4*c3 (windows M=2,3)
      do_pair<0>(Lv, ub, sb0 + c3, acc);
      do_pair<2>(Lv, ub, sb0 + c3, acc);
    }
    do_single(Lv, ub, sb0 + 3, acc);   // dx = +6
  }

  float* dst = out + (size_t)plane * (HH * WW)
             + (size_t)(ty0 + 6 * ty) * WW + (tx0 + 4 * tx);
#define OUTK(K) { float4 o; \
  o.x = acc.n##K.x / acc.d##K.x; o.y = acc.n##K.y / acc.d##K.y; \
  o.z = acc.n##K.z / acc.d##K.z; o.w = acc.n##K.w / acc.d##K.w; \
  *reinterpret_cast<float4*>(dst + (K) * WW) = o; }
  OUTK(0) OUTK(1) OUTK(2) OUTK(3) OUTK(4) OUTK(5)
#undef OUTK
}

extern "C" void kernel_launch(void* const* d_in, const int* in_sizes, int n_in,
                              void* d_out, int out_size, void* d_ws, size_t ws_size,
                              hipStream_t stream) {
  const float* x = (const float*)d_in[0];
  float* out = (float*)d_out;
  dim3 grid(WW / TW, HH / TH, 32);   // 12 x 8 x 32 = 3072 blocks
  dim3 block(16, 16);
  nlm_kernel<<<grid, block, 0, stream>>>(x, out);
}

// Round 6
// 4611.924 us; speedup vs baseline: 4.8921x; 2.6534x over previous
//
#include <hip/hip_runtime.h>

// Fast-mode NLM, PATCH=5 (o=2), DIST=6 -> 169 shifts, h=0.05.
// w = exp(-16*boxsum) = exp2(NEGC*boxsum), NEGC = -16*log2(e).
//
// Round-4 design (resubmit x2; R4/R5 benches were infra timeouts, no data):
// fit under the EMPIRICAL 128-VGPR ceiling (R2/R3 both spilled with the
// allocator refusing >128 arch VGPRs). State cuts vs R3:
//  * STRIP 6 -> 4 (tile 64x64): acc 48 -> 32 regs, LDS 37.9 -> 26.9 KB
//  * ring+dsum (48 regs) -> direct box accumulators (32 regs): each row-sum
//    event adds into the <=4 box sums it covers; no sliding window state
//  * value-ring (15 regs) -> direct aligned float4 re-reads at STEPP
// Persistent ~64 regs, peak ~105-110. All indexing compile-time (rule #20).

#define HH 768
#define WW 768
#define TW 64
#define TH 64
#define LR 80             // TH + 16
#define LSF 84            // LDS row stride in dwords (multiple of 4)
#define LS4 21            // row stride in float4
#define NEGC (-23.083120654223414f)   // -16 * log2(e)

__device__ __forceinline__ float sqf(float t){ return t*t; }

template<int I>
__device__ __forceinline__ float g3(const float4& a, const float4& b, const float4& c){
  if constexpr (I==0) return a.x; else if constexpr (I==1) return a.y;
  else if constexpr (I==2) return a.z; else if constexpr (I==3) return a.w;
  else if constexpr (I==4) return b.x; else if constexpr (I==5) return b.y;
  else if constexpr (I==6) return b.z; else if constexpr (I==7) return b.w;
  else if constexpr (I==8) return c.x; else if constexpr (I==9) return c.y;
  else if constexpr (I==10) return c.z; else return c.w;
}

struct Acc { float4 n0,n1,n2,n3, d0,d1,d2,d3; };

// squared diff: u-window position UI (2..9), s-window position SI
#define SQA(UI,SI) sqf(g3<(UI)>(u0,u1,u2) - g3<(SI)>(s0,s1,s2))

// horizontal 5-window sliding row sums for 4 output cols; O=0 (shift a) / 1 (shift b)
#define QROW(RN, O) \
  { float q0=SQA(2,M+0+O), q1=SQA(3,M+1+O), q2=SQA(4,M+2+O), q3=SQA(5,M+3+O), \
          q4=SQA(6,M+4+O), q5=SQA(7,M+5+O), q6=SQA(8,M+6+O), q7=SQA(9,M+7+O); \
    RN.x = ((q0+q1)+(q2+q3))+q4; \
    RN.y = RN.x - q0 + q5; \
    RN.z = RN.y - q1 + q6; \
    RN.w = RN.z - q2 + q7; }

#define A4(D,S) D.x += S.x; D.y += S.y; D.z += S.z; D.w += S.w;

// one row event for a dx-pair: 6 aligned b128 reads, two row-sums, box adds
#define EVP(E, CODE) { \
  const float4 u0 = Lv[ub + (E)*LS4    ]; \
  const float4 u1 = Lv[ub + (E)*LS4 + 1]; \
  const float4 u2 = Lv[ub + (E)*LS4 + 2]; \
  const float4 s0 = Lv[sb + (E)*LS4    ]; \
  const float4 s1 = Lv[sb + (E)*LS4 + 1]; \
  const float4 s2 = Lv[sb + (E)*LS4 + 2]; \
  float4 ran, rbn; \
  QROW(ran, 0) \
  QROW(rbn, 1) \
  CODE }

// emit output row K for the pair; values re-read from LDS (2 aligned f4)
#define STEPP(K) { \
  const float4 v0 = Lv[sb + ((K)+2)*LS4 + V0]; \
  const float4 v1 = Lv[sb + ((K)+2)*LS4 + V0 + 1]; \
  float4 wa, wb; \
  wa.x = __builtin_amdgcn_exp2f(b##K.x * NEGC); \
  wa.y = __builtin_amdgcn_exp2f(b##K.y * NEGC); \
  wa.z = __builtin_amdgcn_exp2f(b##K.z * NEGC); \
  wa.w = __builtin_amdgcn_exp2f(b##K.w * NEGC); \
  wb.x = __builtin_amdgcn_exp2f(e##K.x * NEGC); \
  wb.y = __builtin_amdgcn_exp2f(e##K.y * NEGC); \
  wb.z = __builtin_amdgcn_exp2f(e##K.z * NEGC); \
  wb.w = __builtin_amdgcn_exp2f(e##K.w * NEGC); \
  acc.n##K.x += wa.x*g3<VI+0>(v0,v1,v1) + wb.x*g3<VI+1>(v0,v1,v1); \
  acc.n##K.y += wa.y*g3<VI+1>(v0,v1,v1) + wb.y*g3<VI+2>(v0,v1,v1); \
  acc.n##K.z += wa.z*g3<VI+2>(v0,v1,v1) + wb.z*g3<VI+3>(v0,v1,v1); \
  acc.n##K.w += wa.w*g3<VI+3>(v0,v1,v1) + wb.w*g3<VI+4>(v0,v1,v1); \
  acc.d##K.x += wa.x + wb.x; acc.d##K.y += wa.y + wb.y; \
  acc.d##K.z += wa.z + wb.z; acc.d##K.w += wa.w + wb.w; }

template<int M>
__device__ __forceinline__ void do_pair(const float4* __restrict__ Lv, int ub, int sb, Acc& acc)
{
  constexpr int V0 = (M+2) >> 2;
  constexpr int VI = (M+2) & 3;
  float4 b0{},b1{},b2{},b3{};   // a-channel boxes (rows 0..3 x 4 cols)
  float4 e0{},e1{},e2{},e3{};   // b-channel boxes
  EVP(0, A4(b0,ran)                                  A4(e0,rbn))
  EVP(1, A4(b0,ran) A4(b1,ran)                       A4(e0,rbn) A4(e1,rbn))
  EVP(2, A4(b0,ran) A4(b1,ran) A4(b2,ran)            A4(e0,rbn) A4(e1,rbn) A4(e2,rbn))
  EVP(3, A4(b0,ran) A4(b1,ran) A4(b2,ran) A4(b3,ran) A4(e0,rbn) A4(e1,rbn) A4(e2,rbn) A4(e3,rbn))
  EVP(4, A4(b0,ran) A4(b1,ran) A4(b2,ran) A4(b3,ran) A4(e0,rbn) A4(e1,rbn) A4(e2,rbn) A4(e3,rbn))
  STEPP(0)
  EVP(5,            A4(b1,ran) A4(b2,ran) A4(b3,ran)            A4(e1,rbn) A4(e2,rbn) A4(e3,rbn))
  STEPP(1)
  EVP(6,                       A4(b2,ran) A4(b3,ran)                       A4(e2,rbn) A4(e3,rbn))
  STEPP(2)
  EVP(7,                                  A4(b3,ran)                                  A4(e3,rbn))
  STEPP(3)
}

// ---- single-shift variant (dx = +6, M = 0): only the a-channel, s2 unused ----
#define EVS(E, CODE) { \
  const float4 u0 = Lv[ub + (E)*LS4    ]; \
  const float4 u1 = Lv[ub + (E)*LS4 + 1]; \
  const float4 u2 = Lv[ub + (E)*LS4 + 2]; \
  const float4 s0 = Lv[sb + (E)*LS4    ]; \
  const float4 s1 = Lv[sb + (E)*LS4 + 1]; \
  const float4& s2 = s1; /* SI max = 7 for M=0: never referenced */ \
  float4 ran; \
  QROW(ran, 0) \
  CODE }

#define STEPS(K) { \
  const float4 v0 = Lv[sb + ((K)+2)*LS4    ]; \
  const float4 v1 = Lv[sb + ((K)+2)*LS4 + 1]; \
  float4 wa; \
  wa.x = __builtin_amdgcn_exp2f(b##K.x * NEGC); \
  wa.y = __builtin_amdgcn_exp2f(b##K.y * NEGC); \
  wa.z = __builtin_amdgcn_exp2f(b##K.z * NEGC); \
  wa.w = __builtin_amdgcn_exp2f(b##K.w * NEGC); \
  acc.n##K.x += wa.x*g3<2>(v0,v1,v1); \
  acc.n##K.y += wa.y*g3<3>(v0,v1,v1); \
  acc.n##K.z += wa.z*g3<4>(v0,v1,v1); \
  acc.n##K.w += wa.w*g3<5>(v0,v1,v1); \
  acc.d##K.x += wa.x; acc.d##K.y += wa.y; \
  acc.d##K.z += wa.z; acc.d##K.w += wa.w; }

__device__ __forceinline__ void do_single(const float4* __restrict__ Lv, int ub, int sb, Acc& acc)
{
  constexpr int M = 0;
  float4 b0{},b1{},b2{},b3{};
  EVS(0, A4(b0,ran))
  EVS(1, A4(b0,ran) A4(b1,ran))
  EVS(2, A4(b0,ran) A4(b1,ran) A4(b2,ran))
  EVS(3, A4(b0,ran) A4(b1,ran) A4(b2,ran) A4(b3,ran))
  EVS(4, A4(b0,ran) A4(b1,ran) A4(b2,ran) A4(b3,ran))
  STEPS(0)
  EVS(5,            A4(b1,ran) A4(b2,ran) A4(b3,ran))
  STEPS(1)
  EVS(6,                       A4(b2,ran) A4(b3,ran))
  STEPS(2)
  EVS(7,                                  A4(b3,ran))
  STEPS(3)
}

__global__ __launch_bounds__(256, 2)
void nlm_kernel(const float* __restrict__ in, float* __restrict__ out)
{
  __shared__ float4 Lv[LR * LS4];
  float* Lf = (float*)Lv;

  const int plane = blockIdx.z;
  const int ty0 = blockIdx.y * TH;
  const int tx0 = blockIdx.x * TW;
  const float* __restrict__ src = in + (size_t)plane * (HH * WW);

  // stage 80x80 reflect-padded, clipped tile (dword cols 80..83 unused)
  const int tid = threadIdx.y * 16 + threadIdx.x;
  for (int idx = tid; idx < LR * 80; idx += 256) {
    int r = idx / 80;
    int c = idx - r * 80;
    int gy = ty0 - 8 + r;
    int gx = tx0 - 8 + c;
    gy = (gy < 0) ? -gy : ((gy >= HH) ? 2 * HH - 2 - gy : gy);
    gx = (gx < 0) ? -gx : ((gx >= WW) ? 2 * WW - 2 - gx : gx);
    float v = src[gy * WW + gx];
    Lf[r * LSF + c] = fminf(fmaxf(v, 0.0f), 1.0f);
  }
  __syncthreads();

  const int tx = threadIdx.x;          // 4 output cols: LDS dwords 4tx+8..4tx+11
  const int ty = threadIdx.y;          // 4 output rows starting at 4*ty
  const int ub = (4 * ty + 6) * LS4 + tx + 1;   // f4 idx of u-read row base

  Acc acc{};

#pragma unroll 1
  for (int dy = -6; dy <= 6; ++dy) {
    const int sb0 = ub - 1 + dy * LS4;
#pragma unroll 1
    for (int c3 = 0; c3 < 3; ++c3) {
      // dx = -6+4*c3 (M=0: shifts dx, dx+1) and dx = -4+4*c3 (M=2)
      do_pair<0>(Lv, ub, sb0 + c3, acc);
      do_pair<2>(Lv, ub, sb0 + c3, acc);
    }
    do_single(Lv, ub, sb0 + 3, acc);   // dx = +6
  }

  float* dst = out + (size_t)plane * (HH * WW)
             + (size_t)(ty0 + 4 * ty) * WW + (tx0 + 4 * tx);
#define OUTK(K) { float4 o; \
  o.x = acc.n##K.x / acc.d##K.x; o.y = acc.n##K.y / acc.d##K.y; \
  o.z = acc.n##K.z / acc.d##K.z; o.w = acc.n##K.w / acc.d##K.w; \
  *reinterpret_cast<float4*>(dst + (K) * WW) = o; }
  OUTK(0) OUTK(1) OUTK(2) OUTK(3)
#undef OUTK
}

extern "C" void kernel_launch(void* const* d_in, const int* in_sizes, int n_in,
                              void* d_out, int out_size, void* d_ws, size_t ws_size,
                              hipStream_t stream) {
  const float* x = (const float*)d_in[0];
  float* out = (float*)d_out;
  dim3 grid(WW / TW, HH / TH, 32);   // 12 x 12 x 32 = 4608 blocks
  dim3 block(16, 16);
  nlm_kernel<<<grid, block, 0, stream>>>(x, out);
}

// Round 7
// 2315.114 us; speedup vs baseline: 9.7456x; 1.9921x over previous
//
#include <hip/hip_runtime.h>

// Fast-mode NLM, PATCH=5 (o=2), DIST=6 -> 169 shifts, h=0.05.
// w = exp(-16*boxsum) = exp2(NEGC*boxsum), NEGC = -16*log2(e).
//
// Round-7: STRIP 4 -> 3. R3/R6 establish the allocator self-caps at 128
// arch VGPRs and demotes the rest to scratch (R6: 16.6 GB spill traffic =
// the whole runtime). Honest R6 peak ~112 + scheduler slack > 128. STRIP=3
// cuts acc 32->24 and boxes 32->24: minimum live ~96, peak ~110-115 < 128.
// Tile 64x48, thread = 4 cols x 3 rows, dx-paired shifts, all static idx.

#define HH 768
#define WW 768
#define TW 64
#define TH 48
#define LR 64             // TH + 16
#define LSF 84            // LDS row stride in dwords (multiple of 4)
#define LS4 21            // row stride in float4
#define NEGC (-23.083120654223414f)   // -16 * log2(e)

__device__ __forceinline__ float sqf(float t){ return t*t; }

template<int I>
__device__ __forceinline__ float g3(const float4& a, const float4& b, const float4& c){
  if constexpr (I==0) return a.x; else if constexpr (I==1) return a.y;
  else if constexpr (I==2) return a.z; else if constexpr (I==3) return a.w;
  else if constexpr (I==4) return b.x; else if constexpr (I==5) return b.y;
  else if constexpr (I==6) return b.z; else if constexpr (I==7) return b.w;
  else if constexpr (I==8) return c.x; else if constexpr (I==9) return c.y;
  else if constexpr (I==10) return c.z; else return c.w;
}

struct Acc { float4 n0,n1,n2, d0,d1,d2; };

// squared diff: u-window position UI (2..9), s-window position SI
#define SQA(UI,SI) sqf(g3<(UI)>(u0,u1,u2) - g3<(SI)>(s0,s1,s2))

// horizontal 5-window sliding row sums for 4 output cols; O=0 (shift a) / 1 (shift b)
#define QROW(RN, O) \
  { float q0=SQA(2,M+0+O), q1=SQA(3,M+1+O), q2=SQA(4,M+2+O), q3=SQA(5,M+3+O), \
          q4=SQA(6,M+4+O), q5=SQA(7,M+5+O), q6=SQA(8,M+6+O), q7=SQA(9,M+7+O); \
    RN.x = ((q0+q1)+(q2+q3))+q4; \
    RN.y = RN.x - q0 + q5; \
    RN.z = RN.y - q1 + q6; \
    RN.w = RN.z - q2 + q7; }

#define A4(D,S) D.x += S.x; D.y += S.y; D.z += S.z; D.w += S.w;

// one row event for a dx-pair: 6 aligned b128 reads, two row-sums, box adds
#define EVP(E, CODE) { \
  const float4 u0 = Lv[ub + (E)*LS4    ]; \
  const float4 u1 = Lv[ub + (E)*LS4 + 1]; \
  const float4 u2 = Lv[ub + (E)*LS4 + 2]; \
  const float4 s0 = Lv[sb + (E)*LS4    ]; \
  const float4 s1 = Lv[sb + (E)*LS4 + 1]; \
  const float4 s2 = Lv[sb + (E)*LS4 + 2]; \
  float4 ran, rbn; \
  QROW(ran, 0) \
  QROW(rbn, 1) \
  CODE }

// emit output row K for the pair; values re-read from LDS (2 aligned f4)
#define STEPP(K) { \
  const float4 v0 = Lv[sb + ((K)+2)*LS4 + V0]; \
  const float4 v1 = Lv[sb + ((K)+2)*LS4 + V0 + 1]; \
  float4 wa, wb; \
  wa.x = __builtin_amdgcn_exp2f(b##K.x * NEGC); \
  wa.y = __builtin_amdgcn_exp2f(b##K.y * NEGC); \
  wa.z = __builtin_amdgcn_exp2f(b##K.z * NEGC); \
  wa.w = __builtin_amdgcn_exp2f(b##K.w * NEGC); \
  wb.x = __builtin_amdgcn_exp2f(e##K.x * NEGC); \
  wb.y = __builtin_amdgcn_exp2f(e##K.y * NEGC); \
  wb.z = __builtin_amdgcn_exp2f(e##K.z * NEGC); \
  wb.w = __builtin_amdgcn_exp2f(e##K.w * NEGC); \
  acc.n##K.x += wa.x*g3<VI+0>(v0,v1,v1) + wb.x*g3<VI+1>(v0,v1,v1); \
  acc.n##K.y += wa.y*g3<VI+1>(v0,v1,v1) + wb.y*g3<VI+2>(v0,v1,v1); \
  acc.n##K.z += wa.z*g3<VI+2>(v0,v1,v1) + wb.z*g3<VI+3>(v0,v1,v1); \
  acc.n##K.w += wa.w*g3<VI+3>(v0,v1,v1) + wb.w*g3<VI+4>(v0,v1,v1); \
  acc.d##K.x += wa.x + wb.x; acc.d##K.y += wa.y + wb.y; \
  acc.d##K.z += wa.z + wb.z; acc.d##K.w += wa.w + wb.w; }

template<int M>
__device__ __forceinline__ void do_pair(const float4* __restrict__ Lv, int ub, int sb, Acc& acc)
{
  constexpr int V0 = (M+2) >> 2;
  constexpr int VI = (M+2) & 3;
  float4 b0{},b1{},b2{};   // a-channel boxes (rows 0..2 x 4 cols)
  float4 e0{},e1{},e2{};   // b-channel boxes
  EVP(0, A4(b0,ran)                       A4(e0,rbn))
  EVP(1, A4(b0,ran) A4(b1,ran)            A4(e0,rbn) A4(e1,rbn))
  EVP(2, A4(b0,ran) A4(b1,ran) A4(b2,ran) A4(e0,rbn) A4(e1,rbn) A4(e2,rbn))
  EVP(3, A4(b0,ran) A4(b1,ran) A4(b2,ran) A4(e0,rbn) A4(e1,rbn) A4(e2,rbn))
  EVP(4, A4(b0,ran) A4(b1,ran) A4(b2,ran) A4(e0,rbn) A4(e1,rbn) A4(e2,rbn))
  STEPP(0)
  EVP(5,            A4(b1,ran) A4(b2,ran)            A4(e1,rbn) A4(e2,rbn))
  STEPP(1)
  EVP(6,                       A4(b2,ran)                       A4(e2,rbn))
  STEPP(2)
}

// ---- single-shift variant (dx = +6, M = 0): only the a-channel, s2 unused ----
#define EVS(E, CODE) { \
  const float4 u0 = Lv[ub + (E)*LS4    ]; \
  const float4 u1 = Lv[ub + (E)*LS4 + 1]; \
  const float4 u2 = Lv[ub + (E)*LS4 + 2]; \
  const float4 s0 = Lv[sb + (E)*LS4    ]; \
  const float4 s1 = Lv[sb + (E)*LS4 + 1]; \
  const float4& s2 = s1; /* SI max = 7 for M=0: never referenced */ \
  float4 ran; \
  QROW(ran, 0) \
  CODE }

#define STEPS(K) { \
  const float4 v0 = Lv[sb + ((K)+2)*LS4    ]; \
  const float4 v1 = Lv[sb + ((K)+2)*LS4 + 1]; \
  float4 wa; \
  wa.x = __builtin_amdgcn_exp2f(b##K.x * NEGC); \
  wa.y = __builtin_amdgcn_exp2f(b##K.y * NEGC); \
  wa.z = __builtin_amdgcn_exp2f(b##K.z * NEGC); \
  wa.w = __builtin_amdgcn_exp2f(b##K.w * NEGC); \
  acc.n##K.x += wa.x*g3<2>(v0,v1,v1); \
  acc.n##K.y += wa.y*g3<3>(v0,v1,v1); \
  acc.n##K.z += wa.z*g3<4>(v0,v1,v1); \
  acc.n##K.w += wa.w*g3<5>(v0,v1,v1); \
  acc.d##K.x += wa.x; acc.d##K.y += wa.y; \
  acc.d##K.z += wa.z; acc.d##K.w += wa.w; }

__device__ __forceinline__ void do_single(const float4* __restrict__ Lv, int ub, int sb, Acc& acc)
{
  constexpr int M = 0;
  float4 b0{},b1{},b2{};
  EVS(0, A4(b0,ran))
  EVS(1, A4(b0,ran) A4(b1,ran))
  EVS(2, A4(b0,ran) A4(b1,ran) A4(b2,ran))
  EVS(3, A4(b0,ran) A4(b1,ran) A4(b2,ran))
  EVS(4, A4(b0,ran) A4(b1,ran) A4(b2,ran))
  STEPS(0)
  EVS(5,            A4(b1,ran) A4(b2,ran))
  STEPS(1)
  EVS(6,                       A4(b2,ran))
  STEPS(2)
}

__global__ __launch_bounds__(256, 2)
void nlm_kernel(const float* __restrict__ in, float* __restrict__ out)
{
  __shared__ float4 Lv[LR * LS4];
  float* Lf = (float*)Lv;

  const int plane = blockIdx.z;
  const int ty0 = blockIdx.y * TH;
  const int tx0 = blockIdx.x * TW;
  const float* __restrict__ src = in + (size_t)plane * (HH * WW);

  // stage 64x80 reflect-padded, clipped tile (dword cols 80..83 unused)
  const int tid = threadIdx.y * 16 + threadIdx.x;
  for (int idx = tid; idx < LR * 80; idx += 256) {
    int r = idx / 80;
    int c = idx - r * 80;
    int gy = ty0 - 8 + r;
    int gx = tx0 - 8 + c;
    gy = (gy < 0) ? -gy : ((gy >= HH) ? 2 * HH - 2 - gy : gy);
    gx = (gx < 0) ? -gx : ((gx >= WW) ? 2 * WW - 2 - gx : gx);
    float v = src[gy * WW + gx];
    Lf[r * LSF + c] = fminf(fmaxf(v, 0.0f), 1.0f);
  }
  __syncthreads();

  const int tx = threadIdx.x;          // 4 output cols: LDS dwords 4tx+8..4tx+11
  const int ty = threadIdx.y;          // 3 output rows starting at 3*ty
  const int ub = (3 * ty + 6) * LS4 + tx + 1;   // f4 idx of u-read row base

  Acc acc{};

#pragma unroll 1
  for (int dy = -6; dy <= 6; ++dy) {
    const int sb0 = ub - 1 + dy * LS4;
#pragma unroll 1
    for (int c3 = 0; c3 < 3; ++c3) {
      // dx = -6+4*c3 (M=0: shifts dx, dx+1) and dx = -4+4*c3 (M=2)
      do_pair<0>(Lv, ub, sb0 + c3, acc);
      do_pair<2>(Lv, ub, sb0 + c3, acc);
    }
    do_single(Lv, ub, sb0 + 3, acc);   // dx = +6
  }

  float* dst = out + (size_t)plane * (HH * WW)
             + (size_t)(ty0 + 3 * ty) * WW + (tx0 + 4 * tx);
#define OUTK(K) { float4 o; \
  o.x = acc.n##K.x / acc.d##K.x; o.y = acc.n##K.y / acc.d##K.y; \
  o.z = acc.n##K.z / acc.d##K.z; o.w = acc.n##K.w / acc.d##K.w; \
  *reinterpret_cast<float4*>(dst + (K) * WW) = o; }
  OUTK(0) OUTK(1) OUTK(2)
#undef OUTK
}

extern "C" void kernel_launch(void* const* d_in, const int* in_sizes, int n_in,
                              void* d_out, int out_size, void* d_ws, size_t ws_size,
                              hipStream_t stream) {
  const float* x = (const float*)d_in[0];
  float* out = (float*)d_out;
  dim3 grid(WW / TW, HH / TH, 32);   // 12 x 16 x 32 = 6144 blocks
  dim3 block(16, 16);
  nlm_kernel<<<grid, block, 0, stream>>>(x, out);
}